// Round 2
// baseline (237.748 us; speedup 1.0000x reference)
//
#include <hip/hip_runtime.h>

#define NB 32
#define NN 2048
#define NC 16
#define ND 128
#define NH 128
#define NK 384
#define TM 32
#define NBLK (NB * (NN / TM))   // 2048

typedef __bf16 bf16x8 __attribute__((ext_vector_type(8)));
typedef float f32x4 __attribute__((ext_vector_type(4)));

__device__ __forceinline__ unsigned short f2bf(float f){
  unsigned u = __float_as_uint(f);
  u = (u + 0x7fffu + ((u >> 16) & 1u)) >> 16;   // RNE
  return (unsigned short)u;
}
__device__ __forceinline__ unsigned enc_f32(float x){
  unsigned u = __float_as_uint(x);
  return (u & 0x80000000u) ? ~u : (u | 0x80000000u);
}
__device__ __forceinline__ float dec_f32(unsigned u){
  return __uint_as_float((u & 0x80000000u) ? (u & 0x7fffffffu) : ~u);
}

// store 8 bf16 (one 16B chunk) into swizzled wf LDS (row stride 768B)
__device__ __forceinline__ void st8(unsigned char* base, int row, int koff, const float* f){
  uint4 u;
  u.x = (unsigned)f2bf(f[0]) | ((unsigned)f2bf(f[1]) << 16);
  u.y = (unsigned)f2bf(f[2]) | ((unsigned)f2bf(f[3]) << 16);
  u.z = (unsigned)f2bf(f[4]) | ((unsigned)f2bf(f[5]) << 16);
  u.w = (unsigned)f2bf(f[6]) | ((unsigned)f2bf(f[7]) << 16);
  *(uint4*)(base + row*768 + (koff ^ ((row & 7) << 4))) = u;
}

// ---- prep: W1 (384x128 f32) -> bf16 fragments in exact B-frag lane order ----
// layout: [cf 0..7][ks 0..11][lane 0..63] x 16B
// col = (cf>>1)*32 + (cf&1)*16 + (lane&15); k = ks*32 + (lane>>4)*8 + j
__global__ __launch_bounds__(256) void prep_w1(const float* __restrict__ W1,
                                               uint4* __restrict__ w1frag,
                                               unsigned* __restrict__ pooled){
  int tt = blockIdx.x * 256 + threadIdx.x;
  if (tt < NB * NH) pooled[tt] = 0u;   // enc-min (any real value wins)
  if (tt >= 8 * 12 * 64) return;
  int lane = tt & 63;
  int rest = tt >> 6;
  int ks = rest % 12;
  int cf = rest / 12;
  int col = (cf >> 1) * 32 + (cf & 1) * 16 + (lane & 15);
  int k0 = ks * 32 + (lane >> 4) * 8;
  unsigned ps[4];
  #pragma unroll
  for (int p = 0; p < 4; ++p){
    unsigned lo = f2bf(W1[(size_t)(k0 + 2*p) * NH + col]);
    unsigned hi = f2bf(W1[(size_t)(k0 + 2*p + 1) * NH + col]);
    ps[p] = lo | (hi << 16);
  }
  w1frag[tt] = make_uint4(ps[0], ps[1], ps[2], ps[3]);
}

// ---- main: gather + wf build (LDS) + bf16 MFMA GEMM + row-max + atomicMax ----
__global__ __launch_bounds__(256, 4) void tbcnn_main(
    const int* __restrict__ children, const float* __restrict__ nodeEmb,
    const uint4* __restrict__ w1frag, unsigned* __restrict__ pooled)
{
  __shared__ __align__(16) unsigned char wf_raw[TM * 768];   // 24 KB
  // XCD-aware swizzle: 2048 blocks = 8 XCDs x 256; each XCD owns 4 batches
  const int j0 = ((blockIdx.x & 7) << 8) | (blockIdx.x >> 3);
  const int b    = j0 >> 6;
  const int tile = j0 & 63;
  const int n0 = tile * TM;
  const int t = threadIdx.x;
  const int lane = t & 63;
  const int w = t >> 6;

  // ---- gather phase: 8 threads per node, 16 dims each ----
  {
    const int nloc = t >> 3;
    const int q = t & 7;
    const int d0 = q * 16;
    const int gn = n0 + nloc;
    const float* embb = nodeEmb + (size_t)b * (NN * ND);
    const int* chp = children + ((size_t)b * NN + gn) * NC;
    int ci[NC];
    #pragma unroll
    for (int c4 = 0; c4 < 4; ++c4){
      int4 v = *(const int4*)(chp + c4 * 4);
      ci[c4*4+0] = v.x; ci[c4*4+1] = v.y; ci[c4*4+2] = v.z; ci[c4*4+3] = v.w;
    }
    int ns = 0;
    #pragma unroll
    for (int c = 0; c < NC; ++c) ns += (ci[c] > 0) ? 1 : 0;
    const float rdiv = 1.0f / (float)(((ns - 1) > 1) ? (ns - 1) : 1);
    const bool one_sib = (ns == 1);

    // self vector -> k-block 0 (the "t" part of wf)
    const float* selfp = embb + (size_t)gn * ND + d0;
    {
      float sv[16];
      #pragma unroll
      for (int j = 0; j < 4; ++j){
        float4 s = *(const float4*)(selfp + j * 4);
        sv[j*4+0]=s.x; sv[j*4+1]=s.y; sv[j*4+2]=s.z; sv[j*4+3]=s.w;
      }
      st8(wf_raw, nloc, 2 * d0, sv);
      st8(wf_raw, nloc, 2 * (d0 + 8), sv + 8);
    }

    // children weighted sums (r and l); weights computed on the fly
    float aR[16], aL[16];
    #pragma unroll
    for (int i = 0; i < 16; ++i){ aR[i] = 0.0f; aL[i] = 0.0f; }
    #pragma unroll
    for (int c = 0; c < NC; ++c){
      const float mk  = (ci[c] > 0) ? 1.0f : 0.0f;
      const float wrc = one_sib ? (0.5f * mk) : (mk * (float)c * rdiv);
      const float wlc = (1.0f - wrc) * mk;
      const float* cp = embb + (size_t)ci[c] * ND + d0;  // ci==0 -> weight 0
      #pragma unroll
      for (int j = 0; j < 4; ++j){
        float4 u = *(const float4*)(cp + j * 4);
        aR[j*4+0] += wrc * u.x; aL[j*4+0] += wlc * u.x;
        aR[j*4+1] += wrc * u.y; aL[j*4+1] += wlc * u.y;
        aR[j*4+2] += wrc * u.z; aL[j*4+2] += wlc * u.z;
        aR[j*4+3] += wrc * u.w; aL[j*4+3] += wlc * u.w;
      }
    }
    st8(wf_raw, nloc, 2 * (ND + d0),         aR);
    st8(wf_raw, nloc, 2 * (ND + d0 + 8),     aR + 8);
    st8(wf_raw, nloc, 2 * (2 * ND + d0),     aL);
    st8(wf_raw, nloc, 2 * (2 * ND + d0 + 8), aL + 8);
  }
  __syncthreads();

  // ---- MFMA: 32 rows x 32 cols per wave, K=384; B frags streamed from L2 ----
  f32x4 acc[2][2];
  #pragma unroll
  for (int rf = 0; rf < 2; ++rf){
    acc[rf][0] = (f32x4){0.f, 0.f, 0.f, 0.f};
    acc[rf][1] = (f32x4){0.f, 0.f, 0.f, 0.f};
  }
  #pragma unroll 4
  for (int ks = 0; ks < 12; ++ks){
    bf16x8 B0 = __builtin_bit_cast(bf16x8, w1frag[((w * 2 + 0) * 12 + ks) * 64 + lane]);
    bf16x8 B1 = __builtin_bit_cast(bf16x8, w1frag[((w * 2 + 1) * 12 + ks) * 64 + lane]);
    const int koff = ks * 64 + ((lane >> 4) << 4);
    #pragma unroll
    for (int rf = 0; rf < 2; ++rf){
      const int row = rf * 16 + (lane & 15);
      bf16x8 a = __builtin_bit_cast(bf16x8,
                  *(const uint4*)(wf_raw + row * 768 + (koff ^ ((row & 7) << 4))));
      acc[rf][0] = __builtin_amdgcn_mfma_f32_16x16x32_bf16(a, B0, acc[rf][0], 0, 0, 0);
      acc[rf][1] = __builtin_amdgcn_mfma_f32_16x16x32_bf16(a, B1, acc[rf][1], 0, 0, 0);
    }
  }

  // ---- max over the 32 rows (tanh deferred: monotonic), atomic pool ----
  float m0 = -3.0e38f, m1 = -3.0e38f;
  #pragma unroll
  for (int rf = 0; rf < 2; ++rf)
    #pragma unroll
    for (int i = 0; i < 4; ++i){
      m0 = fmaxf(m0, acc[rf][0][i]);
      m1 = fmaxf(m1, acc[rf][1][i]);
    }
  m0 = fmaxf(m0, __shfl_xor(m0, 16, 64));
  m0 = fmaxf(m0, __shfl_xor(m0, 32, 64));
  m1 = fmaxf(m1, __shfl_xor(m1, 16, 64));
  m1 = fmaxf(m1, __shfl_xor(m1, 32, 64));
  if (lane < 16){
    atomicMax(pooled + b * NH + w * 32 + lane,      enc_f32(m0));
    atomicMax(pooled + b * NH + w * 32 + 16 + lane, enc_f32(m1));
  }
}

// ---- final: tanh(pooled+b1) @ W2 + b2 -> tanh -> cosine(v1, v2) ----
__global__ __launch_bounds__(1024) void tbcnn_final(
    const unsigned* __restrict__ pooled, const float* __restrict__ b1,
    const float* __restrict__ W2, const float* __restrict__ b2,
    float* __restrict__ out)
{
  __shared__ float hs[NB * NH];
  __shared__ float os[NB * NH];
  const int t = threadIdx.x;
  for (int i = t; i < NB * NH; i += 1024){
    hs[i] = tanhf(dec_f32(pooled[i]) + b1[i & 127]);
  }
  __syncthreads();
  {
    const int o  = t & 127;
    const int bg = t >> 7;        // 0..7, each handles 4 batches
    const float bias = b2[o];
    #pragma unroll
    for (int ii = 0; ii < 4; ++ii){
      const int bb = bg * 4 + ii;
      float s = bias;
      #pragma unroll 4
      for (int k = 0; k < NH; ++k) s += hs[bb * NH + k] * W2[k * NH + o];
      os[bb * NH + o] = tanhf(s);
    }
  }
  __syncthreads();
  if (t < 16){
    float s12 = 0.f, s11 = 0.f, s22 = 0.f;
    for (int d = 0; d < NH; ++d){
      float a = os[t * NH + d];
      float c = os[(t + 16) * NH + d];
      s12 += a * c; s11 += a * a; s22 += c * c;
    }
    float n1 = fmaxf(sqrtf(s11), 1e-8f);
    float n2 = fmaxf(sqrtf(s22), 1e-8f);
    out[t] = s12 / (n1 * n2);
  }
}

extern "C" void kernel_launch(void* const* d_in, const int* in_sizes, int n_in,
                              void* d_out, int out_size, void* d_ws, size_t ws_size,
                              hipStream_t stream)
{
  const int*   children = (const int*)d_in[0];
  const float* nodeEmb  = (const float*)d_in[1];
  const float* W1       = (const float*)d_in[2];
  const float* b1       = (const float*)d_in[3];
  const float* W2       = (const float*)d_in[4];
  const float* b2       = (const float*)d_in[5];
  float* out = (float*)d_out;

  unsigned* pooled = (unsigned*)d_ws;                         // 16 KB
  uint4* w1frag    = (uint4*)((char*)d_ws + NB * NH * 4);     // 96 KB

  prep_w1<<<24, 256, 0, stream>>>(W1, w1frag, pooled);
  tbcnn_main<<<NBLK, 256, 0, stream>>>(children, nodeEmb, w1frag, pooled);
  tbcnn_final<<<1, 1024, 0, stream>>>(pooled, b1, W2, b2, out);
}

// Round 3
// 49.450 us; speedup vs baseline: 4.8078x; 4.8078x over previous
//
#include <hip/hip_runtime.h>

#define NB 32
#define NN 2048
#define NC 16
#define ND 128
#define NH 128
#define NK 384
#define TM 32
#define NBLK (NB * (NN / TM))   // 2048

typedef __bf16 bf16x8 __attribute__((ext_vector_type(8)));
typedef float f32x4 __attribute__((ext_vector_type(4)));

__device__ __forceinline__ unsigned short f2bf(float f){
  unsigned u = __float_as_uint(f);
  u = (u + 0x7fffu + ((u >> 16) & 1u)) >> 16;   // RNE
  return (unsigned short)u;
}
__device__ __forceinline__ unsigned enc_f32(float x){
  unsigned u = __float_as_uint(x);
  return (u & 0x80000000u) ? ~u : (u | 0x80000000u);
}
__device__ __forceinline__ float dec_f32(unsigned u){
  return __uint_as_float((u & 0x80000000u) ? (u & 0x7fffffffu) : ~u);
}

// swizzled LDS tile helpers (XOR bank swizzle: byte ^= (row&7)<<4)
__device__ __forceinline__ void stq(unsigned char* base, int stride, int row, int koff, uint4 u){
  *(uint4*)(base + row * stride + (koff ^ ((row & 7) << 4))) = u;
}
__device__ __forceinline__ void st8(unsigned char* base, int stride, int row, int koff, const float* f){
  uint4 u;
  u.x = (unsigned)f2bf(f[0]) | ((unsigned)f2bf(f[1]) << 16);
  u.y = (unsigned)f2bf(f[2]) | ((unsigned)f2bf(f[3]) << 16);
  u.z = (unsigned)f2bf(f[4]) | ((unsigned)f2bf(f[5]) << 16);
  u.w = (unsigned)f2bf(f[6]) | ((unsigned)f2bf(f[7]) << 16);
  stq(base, stride, row, koff, u);
}
__device__ __forceinline__ uint4 ldq(const unsigned char* base, int stride, int row, int koff){
  return *(const uint4*)(base + row * stride + (koff ^ ((row & 7) << 4)));
}

// ws layout
#define OFF_POOLED 0
#define OFF_W1     16384
#define OFF_W2     114688
#define OFF_EMB    147456
#define WS_NEED_BF (147456 + (size_t)NB*NN*ND*2)

// ---- unified prep ----
// blocks [0,2048): nodeEmb f32 -> bf16 (only if doEmb)
// blocks [2048,2072): W1 -> frag layout [cf 0..7][ks 0..11][lane]x16B ; also pooled init
// blocks [2072,2080): W2 -> frag layout [cf 0..7][ks 0..3][lane]x16B
__global__ __launch_bounds__(256) void tbcnn_prep(
    const float* __restrict__ nodeEmb, const float* __restrict__ W1,
    const float* __restrict__ W2, unsigned* __restrict__ pooled,
    uint4* __restrict__ w1frag, uint4* __restrict__ w2frag,
    ushort* __restrict__ embBf, int doEmb)
{
  const int blk = blockIdx.x;
  const int t = threadIdx.x;
  if (blk < 2048){
    if (!doEmb) return;
    const float4* src = (const float4*)nodeEmb;
    const int tid = blk * 256 + t;
    #pragma unroll
    for (int it = 0; it < 4; ++it){
      const int i = tid + it * 524288;            // 2,097,152 float4 total
      float4 v = src[i];
      ushort4 o;
      o.x = f2bf(v.x); o.y = f2bf(v.y); o.z = f2bf(v.z); o.w = f2bf(v.w);
      *(ushort4*)(embBf + (size_t)i * 4) = o;
    }
  } else if (blk < 2072){
    const int tt = (blk - 2048) * 256 + t;        // 0..6143
    if (tt < NB * NH) pooled[tt] = 0u;            // enc-min
    const int lane = tt & 63;
    const int rest = tt >> 6;                     // 0..95
    const int ks = rest % 12;
    const int cf = rest / 12;
    const int col = (cf >> 1) * 32 + (cf & 1) * 16 + (lane & 15);
    const int k0 = ks * 32 + (lane >> 4) * 8;
    unsigned ps[4];
    #pragma unroll
    for (int p = 0; p < 4; ++p){
      unsigned lo = f2bf(W1[(size_t)(k0 + 2*p) * NH + col]);
      unsigned hi = f2bf(W1[(size_t)(k0 + 2*p + 1) * NH + col]);
      ps[p] = lo | (hi << 16);
    }
    w1frag[tt] = make_uint4(ps[0], ps[1], ps[2], ps[3]);
  } else {
    const int tt = (blk - 2072) * 256 + t;        // 0..2047
    const int lane = tt & 63;
    const int rest = tt >> 6;                     // 0..31
    const int ks = rest & 3;
    const int cf = rest >> 2;
    const int col = (cf >> 1) * 32 + (cf & 1) * 16 + (lane & 15);
    const int k0 = ks * 32 + (lane >> 4) * 8;
    unsigned ps[4];
    #pragma unroll
    for (int p = 0; p < 4; ++p){
      unsigned lo = f2bf(W2[(size_t)(k0 + 2*p) * NH + col]);
      unsigned hi = f2bf(W2[(size_t)(k0 + 2*p + 1) * NH + col]);
      ps[p] = lo | (hi << 16);
    }
    w2frag[tt] = make_uint4(ps[0], ps[1], ps[2], ps[3]);
  }
}

#define PROCU(u, i) { \
  float lo_ = __uint_as_float((u) << 16); \
  float hi_ = __uint_as_float((u) & 0xffff0000u); \
  aR[(i)]   += wrc * lo_; aL[(i)]   += wlc * lo_; \
  aR[(i)+1] += wrc * hi_; aL[(i)+1] += wlc * hi_; }

// ---- main: gather + wf build (LDS) + bf16 MFMA GEMM + row-max + atomicMax ----
template<bool BF>
__global__ __launch_bounds__(256, 2) void tbcnn_main(
    const int* __restrict__ children, const float* __restrict__ nodeEmb,
    const ushort* __restrict__ embBf, const uint4* __restrict__ w1frag,
    unsigned* __restrict__ pooled)
{
  __shared__ __align__(16) unsigned char wf_raw[TM * 768];   // 24 KB
  // XCD-aware swizzle: 2048 blocks = 8 XCDs x 256; each XCD owns 4 batches
  const int j0 = ((blockIdx.x & 7) << 8) | (blockIdx.x >> 3);
  const int b    = j0 >> 6;
  const int tile = j0 & 63;
  const int n0 = tile * TM;
  const int t = threadIdx.x;
  const int lane = t & 63;
  const int w = t >> 6;

  // ---- gather phase: 8 threads per node, 16 dims each ----
  {
    const int nloc = t >> 3;
    const int q = t & 7;
    const int d0 = q * 16;
    const int gn = n0 + nloc;
    const int4* chp4 = (const int4*)(children + ((size_t)b * NN + gn) * NC);

    int ns = 0;
    #pragma unroll
    for (int c4 = 0; c4 < 4; ++c4){
      int4 v = chp4[c4];
      ns += (v.x > 0) + (v.y > 0) + (v.z > 0) + (v.w > 0);
    }
    const float rdiv = 1.0f / (float)(((ns - 1) > 1) ? (ns - 1) : 1);
    const bool one_sib = (ns == 1);

    // self -> k-block 0 (the "t" part of wf)
    if (BF){
      const ushort* sp = embBf + ((size_t)b * NN + gn) * ND + d0;
      stq(wf_raw, 768, nloc, 2 * d0,       *(const uint4*)sp);
      stq(wf_raw, 768, nloc, 2 * (d0 + 8), *(const uint4*)(sp + 8));
    } else {
      const float* sp = nodeEmb + ((size_t)b * NN + gn) * ND + d0;
      float sv[16];
      #pragma unroll
      for (int j = 0; j < 4; ++j){
        float4 s = *(const float4*)(sp + j * 4);
        sv[j*4+0]=s.x; sv[j*4+1]=s.y; sv[j*4+2]=s.z; sv[j*4+3]=s.w;
      }
      st8(wf_raw, 768, nloc, 2 * d0, sv);
      st8(wf_raw, 768, nloc, 2 * (d0 + 8), sv + 8);
    }

    // children weighted sums
    float aR[16], aL[16];
    #pragma unroll
    for (int i = 0; i < 16; ++i){ aR[i] = 0.0f; aL[i] = 0.0f; }
    #pragma unroll
    for (int c4 = 0; c4 < 4; ++c4){
      int4 v = chp4[c4];                       // L1-hot reload, keeps regs low
      int cidx[4] = {v.x, v.y, v.z, v.w};
      #pragma unroll
      for (int jj = 0; jj < 4; ++jj){
        const int c = c4 * 4 + jj;
        const int idx = cidx[jj];
        const float mk  = (idx > 0) ? 1.0f : 0.0f;
        const float wrc = one_sib ? (0.5f * mk) : (mk * (float)c * rdiv);
        const float wlc = (1.0f - wrc) * mk;
        if (BF){
          const ushort* cp = embBf + ((size_t)b * NN + idx) * ND + d0;
          uint4 u0 = *(const uint4*)cp;
          uint4 u1 = *(const uint4*)(cp + 8);
          PROCU(u0.x, 0)  PROCU(u0.y, 2)  PROCU(u0.z, 4)  PROCU(u0.w, 6)
          PROCU(u1.x, 8)  PROCU(u1.y, 10) PROCU(u1.z, 12) PROCU(u1.w, 14)
        } else {
          const float* cp = nodeEmb + ((size_t)b * NN + idx) * ND + d0;
          #pragma unroll
          for (int j = 0; j < 4; ++j){
            float4 u = *(const float4*)(cp + j * 4);
            aR[j*4+0] += wrc * u.x; aL[j*4+0] += wlc * u.x;
            aR[j*4+1] += wrc * u.y; aL[j*4+1] += wlc * u.y;
            aR[j*4+2] += wrc * u.z; aL[j*4+2] += wlc * u.z;
            aR[j*4+3] += wrc * u.w; aL[j*4+3] += wlc * u.w;
          }
        }
      }
    }
    st8(wf_raw, 768, nloc, 2 * (ND + d0),         aR);
    st8(wf_raw, 768, nloc, 2 * (ND + d0 + 8),     aR + 8);
    st8(wf_raw, 768, nloc, 2 * (2 * ND + d0),     aL);
    st8(wf_raw, 768, nloc, 2 * (2 * ND + d0 + 8), aL + 8);
  }
  __syncthreads();

  // ---- MFMA: 32 rows x 32 cols per wave, K=384; B frags streamed (L2-hot) ----
  f32x4 acc[2][2];
  #pragma unroll
  for (int rf = 0; rf < 2; ++rf){
    acc[rf][0] = (f32x4){0.f, 0.f, 0.f, 0.f};
    acc[rf][1] = (f32x4){0.f, 0.f, 0.f, 0.f};
  }
  #pragma unroll 4
  for (int ks = 0; ks < 12; ++ks){
    bf16x8 B0 = __builtin_bit_cast(bf16x8, w1frag[((w * 2 + 0) * 12 + ks) * 64 + lane]);
    bf16x8 B1 = __builtin_bit_cast(bf16x8, w1frag[((w * 2 + 1) * 12 + ks) * 64 + lane]);
    const int koff = ks * 64 + ((lane >> 4) << 4);
    #pragma unroll
    for (int rf = 0; rf < 2; ++rf){
      const int row = rf * 16 + (lane & 15);
      bf16x8 a = __builtin_bit_cast(bf16x8, ldq(wf_raw, 768, row, koff));
      acc[rf][0] = __builtin_amdgcn_mfma_f32_16x16x32_bf16(a, B0, acc[rf][0], 0, 0, 0);
      acc[rf][1] = __builtin_amdgcn_mfma_f32_16x16x32_bf16(a, B1, acc[rf][1], 0, 0, 0);
    }
  }

  // ---- max over rows (tanh deferred: monotonic), atomic pool ----
  float m0 = -3.0e38f, m1 = -3.0e38f;
  #pragma unroll
  for (int rf = 0; rf < 2; ++rf)
    #pragma unroll
    for (int i = 0; i < 4; ++i){
      m0 = fmaxf(m0, acc[rf][0][i]);
      m1 = fmaxf(m1, acc[rf][1][i]);
    }
  m0 = fmaxf(m0, __shfl_xor(m0, 16, 64));
  m0 = fmaxf(m0, __shfl_xor(m0, 32, 64));
  m1 = fmaxf(m1, __shfl_xor(m1, 16, 64));
  m1 = fmaxf(m1, __shfl_xor(m1, 32, 64));
  if (lane < 16){
    atomicMax(pooled + b * NH + w * 32 + lane,      enc_f32(m0));
    atomicMax(pooled + b * NH + w * 32 + 16 + lane, enc_f32(m1));
  }
}

// ---- final: h=tanh(pooled+b1) -> MFMA h@W2 -> tanh -> cosine(v1,v2) ----
__global__ __launch_bounds__(256) void tbcnn_final(
    const unsigned* __restrict__ pooled, const float* __restrict__ b1,
    const uint4* __restrict__ w2frag, const float* __restrict__ b2,
    float* __restrict__ out)
{
  __shared__ __align__(16) unsigned char hls[NB * 256];   // 32 rows x 128 bf16, swizzled
  __shared__ float os[NB * NH];
  const int t = threadIdx.x;
  const int lane = t & 63;
  const int w = t >> 6;

  // h = tanh(pooled + b1), bf16, A-frag LDS layout
  {
    const int row = t >> 3;          // batch 0..31
    const int q = t & 7;
    const int d0 = q * 16;
    const unsigned* pp = pooled + row * NH + d0;
    const float* bp = b1 + d0;
    float hv[16];
    #pragma unroll
    for (int j = 0; j < 16; ++j) hv[j] = tanhf(dec_f32(pp[j]) + bp[j]);
    st8(hls, 256, row, 2 * d0, hv);
    st8(hls, 256, row, 2 * (d0 + 8), hv + 8);
  }
  __syncthreads();

  // MFMA: 32 rows x 32 cols per wave, K=128
  f32x4 acc[2][2];
  #pragma unroll
  for (int rf = 0; rf < 2; ++rf){
    acc[rf][0] = (f32x4){0.f, 0.f, 0.f, 0.f};
    acc[rf][1] = (f32x4){0.f, 0.f, 0.f, 0.f};
  }
  #pragma unroll
  for (int ks = 0; ks < 4; ++ks){
    bf16x8 B0 = __builtin_bit_cast(bf16x8, w2frag[((w * 2 + 0) * 4 + ks) * 64 + lane]);
    bf16x8 B1 = __builtin_bit_cast(bf16x8, w2frag[((w * 2 + 1) * 4 + ks) * 64 + lane]);
    const int koff = ks * 64 + ((lane >> 4) << 4);
    #pragma unroll
    for (int rf = 0; rf < 2; ++rf){
      const int row = rf * 16 + (lane & 15);
      bf16x8 a = __builtin_bit_cast(bf16x8, ldq(hls, 256, row, koff));
      acc[rf][0] = __builtin_amdgcn_mfma_f32_16x16x32_bf16(a, B0, acc[rf][0], 0, 0, 0);
      acc[rf][1] = __builtin_amdgcn_mfma_f32_16x16x32_bf16(a, B1, acc[rf][1], 0, 0, 0);
    }
  }

  // os = tanh(acc + b2)
  #pragma unroll
  for (int rf = 0; rf < 2; ++rf)
    #pragma unroll
    for (int cf = 0; cf < 2; ++cf){
      const int col = w * 32 + cf * 16 + (lane & 15);
      const float bias = b2[col];
      #pragma unroll
      for (int i = 0; i < 4; ++i){
        const int r = rf * 16 + (lane >> 4) * 4 + i;
        os[r * NH + col] = tanhf(acc[rf][cf][i] + bias);
      }
    }
  __syncthreads();

  if (t < 16){
    float s12 = 0.f, s11 = 0.f, s22 = 0.f;
    #pragma unroll 4
    for (int d = 0; d < NH; ++d){
      float a = os[t * NH + d];
      float c = os[(t + 16) * NH + d];
      s12 += a * c; s11 += a * a; s22 += c * c;
    }
    float n1 = fmaxf(sqrtf(s11), 1e-8f);
    float n2 = fmaxf(sqrtf(s22), 1e-8f);
    out[t] = s12 / (n1 * n2);
  }
}

extern "C" void kernel_launch(void* const* d_in, const int* in_sizes, int n_in,
                              void* d_out, int out_size, void* d_ws, size_t ws_size,
                              hipStream_t stream)
{
  const int*   children = (const int*)d_in[0];
  const float* nodeEmb  = (const float*)d_in[1];
  const float* W1       = (const float*)d_in[2];
  const float* b1       = (const float*)d_in[3];
  const float* W2       = (const float*)d_in[4];
  const float* b2       = (const float*)d_in[5];
  float* out = (float*)d_out;

  unsigned* pooled = (unsigned*)((char*)d_ws + OFF_POOLED);
  uint4* w1frag    = (uint4*)((char*)d_ws + OFF_W1);
  uint4* w2frag    = (uint4*)((char*)d_ws + OFF_W2);
  ushort* embBf    = (ushort*)((char*)d_ws + OFF_EMB);

  const bool bf = (ws_size >= WS_NEED_BF);

  tbcnn_prep<<<2080, 256, 0, stream>>>(nodeEmb, W1, W2, pooled, w1frag, w2frag, embBf, bf ? 1 : 0);
  if (bf)
    tbcnn_main<true><<<NBLK, 256, 0, stream>>>(children, nodeEmb, embBf, w1frag, pooled);
  else
    tbcnn_main<false><<<NBLK, 256, 0, stream>>>(children, nodeEmb, embBf, w1frag, pooled);
  tbcnn_final<<<1, 256, 0, stream>>>(pooled, b1, w2frag, b2, out);
}